// Round 3
// baseline (305.729 us; speedup 1.0000x reference)
//
#include <hip/hip_runtime.h>

typedef unsigned short u16;
typedef unsigned int u32;
typedef __attribute__((ext_vector_type(8))) short short8;
typedef __attribute__((ext_vector_type(4))) float f32x4;

#define S_LEN 2048
#define EDIM  1024
#define DK    64
#define NHEAD 16

__device__ inline u16 f2bf(float f) {
    u32 u = __builtin_bit_cast(u32, f);
    u += 0x7fffu + ((u >> 16) & 1u);   // RNE
    return (u16)(u >> 16);
}

#define ASYNC16(gp, lp)                                                        \
    __builtin_amdgcn_global_load_lds(                                          \
        (const __attribute__((address_space(1))) u32*)(gp),                    \
        (__attribute__((address_space(3))) u32*)(lp), 16, 0, 0)

// ---------------------------------------------------------------------------
// fp32 -> bf16 convert (vectorized: float4 in, 4x u16 out)
// ---------------------------------------------------------------------------
__global__ __launch_bounds__(256)
void f32_to_bf16(const float* __restrict__ src, u16* __restrict__ dst, int n) {
    const int i = (blockIdx.x * 256 + threadIdx.x) * 4;
    if (i + 3 < n) {
        const float4 v = *(const float4*)(src + i);
        u16 o[4] = { f2bf(v.x), f2bf(v.y), f2bf(v.z), f2bf(v.w) };
        *(ulong1*)(dst + i) = *(ulong1*)o;
    }
}

// ---------------------------------------------------------------------------
// NT GEMM: C[m][n] = sum_k A[m][k] * B[n][k], A bf16, fp32 accum.
// 128x128 tile, BK=32, global_load_lds(16B) staging, 4 waves, 4x4 MFMA/wave.
// BF32: B operand is fp32 in global, staged fp32 to LDS, converted at
//       fragment read (used only when ws_size is tight).
// EPI:  0 = bf16 row-major, 1 = bf16 per-head-transposed VT scatter,
//       2 = fp32 row-major.
// ---------------------------------------------------------------------------
template<int EPI, bool BF32>
__global__ __launch_bounds__(256, 2)
void gemm128(const u16* __restrict__ A, const void* __restrict__ Bv,
             u16* __restrict__ Cb, float* __restrict__ Cf,
             int M, int N, int K) {
    const int tid  = threadIdx.x;
    const int lane = tid & 63;
    const int w    = tid >> 6;     // wave 0..3
    const int quad = lane >> 4;
    const int l16  = lane & 15;
    const int wm   = w >> 1;       // wave row 0..1 (64 rows each)
    const int wn   = w & 1;        // wave col 0..1
    const int m0   = blockIdx.y * 128;
    const int n0   = blockIdx.x * 128;

    __shared__ u16 lA[128 * 32];
    __shared__ __align__(16) char lBraw[BF32 ? 128 * 32 * 4 : 128 * 32 * 2];

    f32x4 acc[4][4] = {};

    for (int k0 = 0; k0 < K; k0 += 32) {
        __syncthreads();
        // stage A (bf16): per wave 32 rows, 2 issues of 16 rows
#pragma unroll
        for (int i = 0; i < 2; ++i) {
            const int row = w * 32 + i * 16 + (lane >> 2);
            const int col = (lane & 3) * 8;
            ASYNC16(A + (size_t)(m0 + row) * K + k0 + col,
                    &lA[(w * 32 + i * 16) * 32]);
        }
        if (BF32) {
            const float* Bp = (const float*)Bv;
            float*       lB = (float*)lBraw;
#pragma unroll
            for (int i = 0; i < 4; ++i) {
                const int row = w * 32 + i * 8 + (lane >> 3);
                const int col = (lane & 7) * 4;
                ASYNC16(Bp + (size_t)(n0 + row) * K + k0 + col,
                        &lB[(w * 32 + i * 8) * 32]);
            }
        } else {
            const u16* Bp = (const u16*)Bv;
            u16*       lB = (u16*)lBraw;
#pragma unroll
            for (int i = 0; i < 2; ++i) {
                const int row = w * 32 + i * 16 + (lane >> 2);
                const int col = (lane & 3) * 8;
                ASYNC16(Bp + (size_t)(n0 + row) * K + k0 + col,
                        &lB[(w * 32 + i * 16) * 32]);
            }
        }
        __syncthreads();

        short8 av[4], bv[4];
#pragma unroll
        for (int t = 0; t < 4; ++t)
            av[t] = *(const short8*)&lA[(wm * 64 + t * 16 + l16) * 32 + quad * 8];
        if (BF32) {
            const float* lB = (const float*)lBraw;
#pragma unroll
            for (int t = 0; t < 4; ++t) {
                const float* src = &lB[(wn * 64 + t * 16 + l16) * 32 + quad * 8];
                const f32x4 x0 = *(const f32x4*)src;
                const f32x4 x1 = *(const f32x4*)(src + 4);
                short8 bq;
#pragma unroll
                for (int j = 0; j < 4; ++j) {
                    bq[j]     = (short)f2bf(x0[j]);
                    bq[4 + j] = (short)f2bf(x1[j]);
                }
                bv[t] = bq;
            }
        } else {
            const u16* lB = (const u16*)lBraw;
#pragma unroll
            for (int t = 0; t < 4; ++t)
                bv[t] = *(const short8*)&lB[(wn * 64 + t * 16 + l16) * 32 + quad * 8];
        }

#pragma unroll
        for (int mt = 0; mt < 4; ++mt)
#pragma unroll
            for (int nt = 0; nt < 4; ++nt)
                acc[mt][nt] = __builtin_amdgcn_mfma_f32_16x16x32_bf16(
                    av[mt], bv[nt], acc[mt][nt], 0, 0, 0);
    }

    // epilogue: C/D layout col=lane&15, row=quad*4+reg
#pragma unroll
    for (int mt = 0; mt < 4; ++mt)
#pragma unroll
        for (int nt = 0; nt < 4; ++nt) {
            if (EPI == 1) {
                // V -> VT[(b*16+h)*64+d][s] directly (per-head transpose)
                const int col  = n0 + wn * 64 + nt * 16 + l16;
                const int h    = (col >> 6) & 15;
                const int d    = col & 63;
                const int rowb = m0 + wm * 64 + mt * 16 + quad * 4;
                const int b    = rowb >> 11;
                const int s    = rowb & 2047;
                ushort4 o;
                o.x = f2bf(acc[mt][nt][0]);
                o.y = f2bf(acc[mt][nt][1]);
                o.z = f2bf(acc[mt][nt][2]);
                o.w = f2bf(acc[mt][nt][3]);
                *(ushort4*)&Cb[((size_t)(b * 16 + h) * 64 + d) * S_LEN + s] = o;
            } else {
#pragma unroll
                for (int r = 0; r < 4; ++r) {
                    const int row = m0 + wm * 64 + mt * 16 + quad * 4 + r;
                    const int col = n0 + wn * 64 + nt * 16 + l16;
                    if (EPI == 2)
                        Cf[(size_t)row * N + col] = acc[mt][nt][r];
                    else
                        Cb[(size_t)row * N + col] = f2bf(acc[mt][nt][r]);
                }
            }
        }
}

// ---------------------------------------------------------------------------
// Flash attention per (b, h, 128-row Q tile). Online softmax. Adds quantum
// scalar c to d<4 in the epilogue; writes mixed[b][s][h*64+d] (bf16).
// ---------------------------------------------------------------------------
__global__ __launch_bounds__(256, 2)
void attn_kernel(const u16* __restrict__ Qg, const u16* __restrict__ Kg,
                 const u16* __restrict__ VTg, const float* __restrict__ qp,
                 u16* __restrict__ Mg) {
    const int tid  = threadIdx.x;
    const int lane = tid & 63;
    const int w    = tid >> 6;
    const int quad = lane >> 4;
    const int l16  = lane & 15;
    const int bh   = blockIdx.y;
    const int b    = bh >> 4;
    const int h    = bh & 15;
    const int q0   = blockIdx.x * 128;

    __shared__ u16 lK[64 * 72];      // [j][d], padded rows
    __shared__ u16 lV[64 * 72];      // [d][j], padded rows
    __shared__ u16 lP[4][32 * 72];   // per-wave P rows [m][j], padded

    const float qc = cosf(qp[0] + qp[1]);

    // Q fragments (A-operand): wave owns rows [w*32, w*32+32)
    short8 aq[2][2];
#pragma unroll
    for (int mt = 0; mt < 2; ++mt)
#pragma unroll
        for (int ks = 0; ks < 2; ++ks)
            aq[mt][ks] = *(const short8*)(Qg +
                (size_t)(b * S_LEN + q0 + w * 32 + mt * 16 + l16) * EDIM +
                h * DK + ks * 32 + quad * 8);

    f32x4 oacc[2][4] = {};
    float mi[2][4], li[2][4];
#pragma unroll
    for (int mt = 0; mt < 2; ++mt)
#pragma unroll
        for (int r = 0; r < 4; ++r) { mi[mt][r] = -1e30f; li[mt][r] = 0.f; }

    const int r64  = tid >> 2;
    const int cseg = (tid & 3) * 16;
    u16* lPw = &lP[w][0];

    for (int j0 = 0; j0 < S_LEN; j0 += 64) {
        __syncthreads();   // protect lK/lV from previous iteration's readers
        {
            const u16* sk = Kg + (size_t)(b * S_LEN + j0 + r64) * EDIM + h * DK + cseg;
            short8 v0 = *(const short8*)sk;
            short8 v1 = *(const short8*)(sk + 8);
            *(short8*)&lK[r64 * 72 + cseg]     = v0;
            *(short8*)&lK[r64 * 72 + cseg + 8] = v1;
            const u16* sv = VTg + (size_t)(bh * DK + r64) * S_LEN + j0 + cseg;
            short8 u0 = *(const short8*)sv;
            short8 u1 = *(const short8*)(sv + 8);
            *(short8*)&lV[r64 * 72 + cseg]     = u0;
            *(short8*)&lV[r64 * 72 + cseg + 8] = u1;
        }
        __syncthreads();

        // S = Q K^T for this 128x64 tile (per wave: 32x64)
        f32x4 sacc[2][4] = {};
#pragma unroll
        for (int ks = 0; ks < 2; ++ks) {
            short8 bK[4];
#pragma unroll
            for (int nt = 0; nt < 4; ++nt)
                bK[nt] = *(const short8*)&lK[(nt * 16 + l16) * 72 + ks * 32 + quad * 8];
#pragma unroll
            for (int mt = 0; mt < 2; ++mt)
#pragma unroll
                for (int nt = 0; nt < 4; ++nt)
                    sacc[mt][nt] = __builtin_amdgcn_mfma_f32_16x16x32_bf16(
                        aq[mt][ks], bK[nt], sacc[mt][nt], 0, 0, 0);
        }

        // online softmax; C-layout row = quad*4+r lives in one 16-lane group
#pragma unroll
        for (int mt = 0; mt < 2; ++mt) {
#pragma unroll
            for (int r = 0; r < 4; ++r) {
                float m = -1e30f;
#pragma unroll
                for (int nt = 0; nt < 4; ++nt)
                    m = fmaxf(m, sacc[mt][nt][r] * 0.125f);
                m = fmaxf(m, __shfl_xor(m, 1, 16));
                m = fmaxf(m, __shfl_xor(m, 2, 16));
                m = fmaxf(m, __shfl_xor(m, 4, 16));
                m = fmaxf(m, __shfl_xor(m, 8, 16));
                const float mn = fmaxf(mi[mt][r], m);
                const float al = __expf(mi[mt][r] - mn);
                float rs = 0.f;
#pragma unroll
                for (int nt = 0; nt < 4; ++nt) {
                    const float p = __expf(sacc[mt][nt][r] * 0.125f - mn);
                    lPw[(mt * 16 + quad * 4 + r) * 72 + nt * 16 + l16] = f2bf(p);
                    rs += p;
                }
                rs += __shfl_xor(rs, 1, 16);
                rs += __shfl_xor(rs, 2, 16);
                rs += __shfl_xor(rs, 4, 16);
                rs += __shfl_xor(rs, 8, 16);
                mi[mt][r] = mn;
                li[mt][r] = li[mt][r] * al + rs;
#pragma unroll
                for (int dt = 0; dt < 4; ++dt)
                    oacc[mt][dt][r] *= al;
            }
        }
        __builtin_amdgcn_s_waitcnt(0xc07f);  // lgkmcnt(0): P writes done (wave-private LDS)

        // O += P @ V  (contraction over j; B-operand from VT tile)
#pragma unroll
        for (int ks = 0; ks < 2; ++ks) {
            short8 bV[4];
#pragma unroll
            for (int dt = 0; dt < 4; ++dt)
                bV[dt] = *(const short8*)&lV[(dt * 16 + l16) * 72 + ks * 32 + quad * 8];
#pragma unroll
            for (int mt = 0; mt < 2; ++mt) {
                const short8 aP = *(const short8*)&lPw[(mt * 16 + l16) * 72 + ks * 32 + quad * 8];
#pragma unroll
                for (int dt = 0; dt < 4; ++dt)
                    oacc[mt][dt] = __builtin_amdgcn_mfma_f32_16x16x32_bf16(
                        aP, bV[dt], oacc[mt][dt], 0, 0, 0);
            }
        }
    }

    // epilogue: normalize, add quantum scalar to d<4, store bf16
#pragma unroll
    for (int mt = 0; mt < 2; ++mt)
#pragma unroll
        for (int r = 0; r < 4; ++r) {
            const float inv = 1.f / li[mt][r];
            const int   s   = q0 + w * 32 + mt * 16 + quad * 4 + r;
#pragma unroll
            for (int dt = 0; dt < 4; ++dt) {
                const int d = dt * 16 + l16;
                float val = oacc[mt][dt][r] * inv;
                if (d < 4) val += qc;
                Mg[(size_t)(b * S_LEN + s) * EDIM + h * DK + d] = f2bf(val);
            }
        }
}

// ---------------------------------------------------------------------------
// Workspace budget (the round-2 bug was 48 MB of unchecked d_ws usage):
//   Q,K (bf16, 8 MB each) live in d_out (16 MB fp32 region, dead by the time
//   the final projection overwrites it).
//   fast path (ws >= 18.9 MB): xb/mixed(8) + VT(8) + rotating Wb(2) = 18.9 MB
//   tight path (ws >= 16.0 MB): xb/mixed(8) + VT(8) = 16 MB exactly; weights
//   stay fp32 in global and are converted at fragment read inside the GEMM.
// Host branch depends only on ws_size (constant) -> graph-capture safe.
// ---------------------------------------------------------------------------
extern "C" void kernel_launch(void* const* d_in, const int* in_sizes, int n_in,
                              void* d_out, int out_size, void* d_ws, size_t ws_size,
                              hipStream_t stream) {
    const float* x  = (const float*)d_in[0];
    const float* Wq = (const float*)d_in[1];
    const float* Wk = (const float*)d_in[2];
    const float* Wv = (const float*)d_in[3];
    const float* Wo = (const float*)d_in[4];
    const float* qp = (const float*)d_in[5];

    const size_t BUF  = (size_t)2 * S_LEN * EDIM;   // 4,194,304 elements
    const size_t WBUF = (size_t)EDIM * EDIM;        // 1,048,576 elements

    u16* Q  = (u16*)d_out;          // 8 MB
    u16* Kb = Q + BUF;              // 8 MB (d_out totals 16 MB fp32)

    u16* ws    = (u16*)d_ws;
    u16* xb    = ws;                // 8 MB; dead after QKV -> mixed reuses it
    u16* mixed = xb;
    u16* VT    = ws + BUF;          // 8 MB
    u16* Wb    = ws + 2 * BUF;      // 2 MB (fast path only)
    float* out = (float*)d_out;

    const int M = 2 * S_LEN, N = EDIM, Kd = EDIM;
    const dim3 gg(N / 128, M / 128, 1);
    const bool fast = ws_size >= (size_t)(2 * BUF + WBUF) * sizeof(u16);

    f32_to_bf16<<<(int)(BUF / 1024), 256, 0, stream>>>(x, xb, (int)BUF);

    if (fast) {
        f32_to_bf16<<<(int)(WBUF / 1024), 256, 0, stream>>>(Wq, Wb, (int)WBUF);
        gemm128<0, false><<<gg, 256, 0, stream>>>(xb, Wb, Q, nullptr, M, N, Kd);
        f32_to_bf16<<<(int)(WBUF / 1024), 256, 0, stream>>>(Wk, Wb, (int)WBUF);
        gemm128<0, false><<<gg, 256, 0, stream>>>(xb, Wb, Kb, nullptr, M, N, Kd);
        f32_to_bf16<<<(int)(WBUF / 1024), 256, 0, stream>>>(Wv, Wb, (int)WBUF);
        gemm128<1, false><<<gg, 256, 0, stream>>>(xb, Wb, VT, nullptr, M, N, Kd);
        attn_kernel<<<dim3(S_LEN / 128, 2 * NHEAD), 256, 0, stream>>>(
            Q, Kb, VT, qp, mixed);
        f32_to_bf16<<<(int)(WBUF / 1024), 256, 0, stream>>>(Wo, Wb, (int)WBUF);
        gemm128<2, false><<<gg, 256, 0, stream>>>(mixed, Wb, nullptr, out, M, N, Kd);
    } else {
        gemm128<0, true><<<gg, 256, 0, stream>>>(xb, Wq, Q, nullptr, M, N, Kd);
        gemm128<0, true><<<gg, 256, 0, stream>>>(xb, Wk, Kb, nullptr, M, N, Kd);
        gemm128<1, true><<<gg, 256, 0, stream>>>(xb, Wv, VT, nullptr, M, N, Kd);
        attn_kernel<<<dim3(S_LEN / 128, 2 * NHEAD), 256, 0, stream>>>(
            Q, Kb, VT, qp, mixed);
        gemm128<2, true><<<gg, 256, 0, stream>>>(mixed, Wo, nullptr, out, M, N, Kd);
    }
}

// Round 4
// 219.359 us; speedup vs baseline: 1.3937x; 1.3937x over previous
//
#include <hip/hip_runtime.h>

typedef unsigned short u16;
typedef unsigned int u32;
typedef __attribute__((ext_vector_type(8))) short short8;
typedef __attribute__((ext_vector_type(4))) float f32x4;
typedef __attribute__((ext_vector_type(16))) float f32x16;
typedef __attribute__((ext_vector_type(4))) u32 u32x4;

#define S_LEN 2048
#define EDIM  1024
#define DK    64
#define NHEAD 16
// softmax scale 1/8 folded with log2(e) into the Q projection:
#define QSCALE 0.1803368801111f

__device__ inline u16 f2bf(float f) {
    u32 u = __builtin_bit_cast(u32, f);
    u += 0x7fffu + ((u >> 16) & 1u);   // RNE
    return (u16)(u >> 16);
}
__device__ inline u32 pk2(float a, float b) {   // pack 2 bf16: a -> low
    return (u32)f2bf(a) | ((u32)f2bf(b) << 16);
}

#define ASYNC16(gp, lp)                                                        \
    __builtin_amdgcn_global_load_lds(                                          \
        (const __attribute__((address_space(1))) u32*)(gp),                    \
        (__attribute__((address_space(3))) u32*)(lp), 16, 0, 0)

// ---------------------------------------------------------------------------
// Fused fp32->bf16 converts: segment 0 = x (4M els), 1..3 = Wq/Wk/Wv (1M each)
// ---------------------------------------------------------------------------
__global__ __launch_bounds__(256)
void conv_all(const float* __restrict__ x,  const float* __restrict__ Wq,
              const float* __restrict__ Wk, const float* __restrict__ Wv,
              u16* __restrict__ xb, u16* __restrict__ Wb /*3M contiguous*/) {
    const int blk = blockIdx.x;
    const float* src; u16* dst; int idx;
    if (blk < 4096)      { src = x;  dst = xb;            idx = blk; }
    else if (blk < 5120) { src = Wq; dst = Wb;            idx = blk - 4096; }
    else if (blk < 6144) { src = Wk; dst = Wb + (1 << 20); idx = blk - 5120; }
    else                 { src = Wv; dst = Wb + (2 << 20); idx = blk - 6144; }
    const int i = idx * 1024 + threadIdx.x * 4;
    const float4 v = *(const float4*)(src + i);
    u16 o[4] = { f2bf(v.x), f2bf(v.y), f2bf(v.z), f2bf(v.w) };
    *(ulong1*)(dst + i) = *(ulong1*)o;
}

__global__ __launch_bounds__(256)
void f32_to_bf16(const float* __restrict__ src, u16* __restrict__ dst, int n) {
    const int i = (blockIdx.x * 256 + threadIdx.x) * 4;
    if (i + 3 < n) {
        const float4 v = *(const float4*)(src + i);
        u16 o[4] = { f2bf(v.x), f2bf(v.y), f2bf(v.z), f2bf(v.w) };
        *(ulong1*)(dst + i) = *(ulong1*)o;
    }
}

// ---------------------------------------------------------------------------
// NT GEMM: C[m][n] = sum_k A[m][k]*B[n][k]. 128x128 tile, BK=32,
// global_load_lds(16B), 4 waves, 4x4 16x16x32 MFMA.
// EPI 0 (QKV fused, z selects): z0 -> Q bf16 scaled by QSCALE, z1 -> K bf16,
//   z2 -> V scattered to VT[(b*16+h)*64+d][s].   EPI 2: fp32 row-major.
// BF32: B is fp32 in global, staged fp32, converted at fragment read.
// ---------------------------------------------------------------------------
template<int EPI, bool BF32>
__global__ __launch_bounds__(256, 2)
void gemm128(const u16* __restrict__ A,
             const void* __restrict__ B0, const void* __restrict__ B1,
             const void* __restrict__ B2,
             u16* __restrict__ C0, u16* __restrict__ C1, u16* __restrict__ C2,
             float* __restrict__ Cf, int M, int N, int K) {
    const void* Bv = B0;
    u16*        Cp = C0;
    float       cscale = (EPI == 0) ? QSCALE : 1.0f;
    if (blockIdx.z == 1) { Bv = B1; Cp = C1; cscale = 1.0f; }
    else if (blockIdx.z == 2) { Bv = B2; Cp = C2; cscale = 1.0f; }

    const int tid  = threadIdx.x;
    const int lane = tid & 63;
    const int w    = tid >> 6;
    const int quad = lane >> 4;
    const int l16  = lane & 15;
    const int wm   = w >> 1;
    const int wn   = w & 1;
    const int m0   = blockIdx.y * 128;
    const int n0   = blockIdx.x * 128;

    __shared__ u16 lA[128 * 32];
    __shared__ __align__(16) char lBraw[BF32 ? 128 * 32 * 4 : 128 * 32 * 2];

    f32x4 acc[4][4] = {};

    for (int k0 = 0; k0 < K; k0 += 32) {
        __syncthreads();
#pragma unroll
        for (int i = 0; i < 2; ++i) {
            const int row = w * 32 + i * 16 + (lane >> 2);
            const int col = (lane & 3) * 8;
            ASYNC16(A + (size_t)(m0 + row) * K + k0 + col,
                    &lA[(w * 32 + i * 16) * 32]);
        }
        if (BF32) {
            const float* Bp = (const float*)Bv;
            float*       lB = (float*)lBraw;
#pragma unroll
            for (int i = 0; i < 4; ++i) {
                const int row = w * 32 + i * 8 + (lane >> 3);
                const int col = (lane & 7) * 4;
                ASYNC16(Bp + (size_t)(n0 + row) * K + k0 + col,
                        &lB[(w * 32 + i * 8) * 32]);
            }
        } else {
            const u16* Bp = (const u16*)Bv;
            u16*       lB = (u16*)lBraw;
#pragma unroll
            for (int i = 0; i < 2; ++i) {
                const int row = w * 32 + i * 16 + (lane >> 2);
                const int col = (lane & 3) * 8;
                ASYNC16(Bp + (size_t)(n0 + row) * K + k0 + col,
                        &lB[(w * 32 + i * 16) * 32]);
            }
        }
        __syncthreads();

        short8 av[4], bv[4];
#pragma unroll
        for (int t = 0; t < 4; ++t)
            av[t] = *(const short8*)&lA[(wm * 64 + t * 16 + l16) * 32 + quad * 8];
        if (BF32) {
            const float* lB = (const float*)lBraw;
#pragma unroll
            for (int t = 0; t < 4; ++t) {
                const float* src = &lB[(wn * 64 + t * 16 + l16) * 32 + quad * 8];
                const f32x4 x0 = *(const f32x4*)src;
                const f32x4 x1 = *(const f32x4*)(src + 4);
                short8 bq;
#pragma unroll
                for (int j = 0; j < 4; ++j) {
                    bq[j]     = (short)f2bf(x0[j]);
                    bq[4 + j] = (short)f2bf(x1[j]);
                }
                bv[t] = bq;
            }
        } else {
            const u16* lB = (const u16*)lBraw;
#pragma unroll
            for (int t = 0; t < 4; ++t)
                bv[t] = *(const short8*)&lB[(wn * 64 + t * 16 + l16) * 32 + quad * 8];
        }

#pragma unroll
        for (int mt = 0; mt < 4; ++mt)
#pragma unroll
            for (int nt = 0; nt < 4; ++nt)
                acc[mt][nt] = __builtin_amdgcn_mfma_f32_16x16x32_bf16(
                    av[mt], bv[nt], acc[mt][nt], 0, 0, 0);
    }

    // epilogue: C/D layout col=lane&15, row=quad*4+reg
#pragma unroll
    for (int mt = 0; mt < 4; ++mt)
#pragma unroll
        for (int nt = 0; nt < 4; ++nt) {
            if (EPI == 0 && blockIdx.z == 2) {
                const int col  = n0 + wn * 64 + nt * 16 + l16;
                const int h    = (col >> 6) & 15;
                const int d    = col & 63;
                const int rowb = m0 + wm * 64 + mt * 16 + quad * 4;
                const int b    = rowb >> 11;
                const int s    = rowb & 2047;
                ushort4 o;
                o.x = f2bf(acc[mt][nt][0]);
                o.y = f2bf(acc[mt][nt][1]);
                o.z = f2bf(acc[mt][nt][2]);
                o.w = f2bf(acc[mt][nt][3]);
                *(ushort4*)&Cp[((size_t)(b * 16 + h) * 64 + d) * S_LEN + s] = o;
            } else {
#pragma unroll
                for (int r = 0; r < 4; ++r) {
                    const int row = m0 + wm * 64 + mt * 16 + quad * 4 + r;
                    const int col = n0 + wn * 64 + nt * 16 + l16;
                    if (EPI == 2)
                        Cf[(size_t)row * N + col] = acc[mt][nt][r];
                    else
                        Cp[(size_t)row * N + col] = f2bf(acc[mt][nt][r] * cscale);
                }
            }
        }
}

// ---------------------------------------------------------------------------
// Attention v2: per (b,h,128-q-tile) block, 4 waves, each wave owns 32 q-rows.
// j-tile = 128. Computes S^T = K·Q^T with 32x32x16 MFMA so P^T lands with
// m in lanes / j in regs == the A-operand shape PV needs; the only data
// movement is a shfl_xor(32) of packed bf16 dwords between wave halves.
// Unstabilized exp2 softmax (scale pre-folded into Q); li summed per-lane,
// reduced once in the epilogue.  No P LDS, no per-iter shuffles.
// ---------------------------------------------------------------------------
__global__ __launch_bounds__(256, 2)
void attn2(const u16* __restrict__ Qg, const u16* __restrict__ Kg,
           const u16* __restrict__ VTg, const float* __restrict__ qp,
           u16* __restrict__ Mg) {
    const int tid  = threadIdx.x;
    const int lane = tid & 63;
    const int w    = tid >> 6;
    const int l32  = lane & 31;
    const int hi   = lane >> 5;
    const int bh   = blockIdx.y;
    const int b    = bh >> 4;
    const int h    = bh & 15;
    const int q0   = blockIdx.x * 128;

    __shared__ u16 lK[128 * 72];     // [j][d], pad 72 (rows 144 B, 16B-aligned)
    __shared__ u16 lV[64 * 136];     // [d][j], pad 136 (rows 272 B)

    const float qc = cosf(qp[0] + qp[1]);

    // Q fragments as MFMA B-operand: B[k=d][n=m], lane = m = w*32+l32,
    // k = kk*16 + hi*8 + i  (identical register layout to an A-frag of Q)
    short8 bq[4];
    {
        const u16* qrow = Qg + (size_t)(b * S_LEN + q0 + w * 32 + l32) * EDIM +
                          h * DK + hi * 8;
#pragma unroll
        for (int kk = 0; kk < 4; ++kk)
            bq[kk] = *(const short8*)(qrow + kk * 16);
    }

    f32x16 oacc[2] = {};   // O^C: lane = d = dt*32+l32, regs = m
    float  li = 0.f;       // per-lane partial row-sum for m = w*32+l32

    const int krow = tid >> 1, kcol = (tid & 1) * 32;
    const int vrow = tid >> 2, vcol = (tid & 3) * 32;

    for (int j0 = 0; j0 < S_LEN; j0 += 128) {
        __syncthreads();
        {
            const u16* ks = Kg + (size_t)(b * S_LEN + j0 + krow) * EDIM +
                            h * DK + kcol;
#pragma unroll
            for (int c = 0; c < 4; ++c)
                *(short8*)&lK[krow * 72 + kcol + c * 8] =
                    *(const short8*)(ks + c * 8);
            const u16* vs = VTg + (size_t)(bh * DK + vrow) * S_LEN + j0 + vcol;
#pragma unroll
            for (int c = 0; c < 4; ++c)
                *(short8*)&lV[vrow * 136 + vcol + c * 8] =
                    *(const short8*)(vs + c * 8);
        }
        __syncthreads();

        // S^T[j][m] = sum_d K[j][d] Q[m][d]   (4 j-tiles of 32)
        f32x16 sT[4] = {};
#pragma unroll
        for (int jt = 0; jt < 4; ++jt)
#pragma unroll
            for (int kk = 0; kk < 4; ++kk) {
                const short8 aK =
                    *(const short8*)&lK[(jt * 32 + l32) * 72 + kk * 16 + hi * 8];
                sT[jt] = __builtin_amdgcn_mfma_f32_32x32x16_bf16(
                    aK, bq[kk], sT[jt], 0, 0, 0);
            }

        // exp2 -> pack -> half-swap -> PV
#pragma unroll
        for (int jt = 0; jt < 4; ++jt) {
            float e[16];
#pragma unroll
            for (int r = 0; r < 16; ++r) {
                e[r] = exp2f(sT[jt][r]);
                li += e[r];
            }
#pragma unroll
            for (int s = 0; s < 2; ++s) {
                const u32 P0 = pk2(e[8 * s + 0], e[8 * s + 1]);
                const u32 P1 = pk2(e[8 * s + 2], e[8 * s + 3]);
                const u32 P2 = pk2(e[8 * s + 4], e[8 * s + 5]);
                const u32 P3 = pk2(e[8 * s + 6], e[8 * s + 7]);
                const u32 XA = (u32)__shfl_xor((int)(hi ? P0 : P2), 32, 64);
                const u32 XB = (u32)__shfl_xor((int)(hi ? P1 : P3), 32, 64);
                u32x4 t;
                t[0] = hi ? XA : P0;
                t[1] = hi ? XB : P1;
                t[2] = hi ? P2 : XA;
                t[3] = hi ? P3 : XB;
                const short8 aP = __builtin_bit_cast(short8, t);
                const int ks = jt * 2 + s;
#pragma unroll
                for (int dt = 0; dt < 2; ++dt) {
                    const short8 bV = *(const short8*)
                        &lV[(dt * 32 + l32) * 136 + ks * 16 + hi * 8];
                    oacc[dt] = __builtin_amdgcn_mfma_f32_32x32x16_bf16(
                        aP, bV, oacc[dt], 0, 0, 0);
                }
            }
        }
    }

    // epilogue: finish li, normalize (li indexed by lane=m, oacc m in regs),
    // add quantum scalar to d<4, store bf16
    li += __shfl_xor(li, 32, 64);
    const float inv = 1.f / li;
#pragma unroll
    for (int r = 0; r < 16; ++r) {
        const int ml   = (r & 3) + 8 * (r >> 2) + 4 * hi;
        const float im = __shfl(inv, ml, 64);
        const int sg   = q0 + w * 32 + ml;
#pragma unroll
        for (int dt = 0; dt < 2; ++dt) {
            const int d = dt * 32 + l32;
            float val = oacc[dt][r] * im;
            if (d < 4) val += qc;
            Mg[(size_t)(b * S_LEN + sg) * EDIM + h * DK + d] = f2bf(val);
        }
    }
}

// ---------------------------------------------------------------------------
// Workspace: path A (ws >= 22 MB): xb[0,8M) + VT[8M,16M) + Wqkv[16M,22M);
//   Wo converted into the Wq slot after the QKV GEMM (stream-ordered).
// path C (ws >= 16 MB): xb + VT only; weights read fp32 inside the GEMM.
// Q,K (bf16, 8 MB each) live in d_out (16 MB fp32), dead before the final
// projection overwrites it.  Host branch depends only on ws_size (constant).
// ---------------------------------------------------------------------------
extern "C" void kernel_launch(void* const* d_in, const int* in_sizes, int n_in,
                              void* d_out, int out_size, void* d_ws, size_t ws_size,
                              hipStream_t stream) {
    const float* x  = (const float*)d_in[0];
    const float* Wq = (const float*)d_in[1];
    const float* Wk = (const float*)d_in[2];
    const float* Wv = (const float*)d_in[3];
    const float* Wo = (const float*)d_in[4];
    const float* qp = (const float*)d_in[5];

    const size_t BUF  = (size_t)2 * S_LEN * EDIM;   // 4M elements
    const size_t WBUF = (size_t)EDIM * EDIM;        // 1M elements

    u16* Q  = (u16*)d_out;
    u16* Kb = Q + BUF;

    u16* ws    = (u16*)d_ws;
    u16* xb    = ws;                 // dead after QKV; mixed reuses it
    u16* mixed = xb;
    u16* VT    = ws + BUF;
    u16* Wqb   = ws + 2 * BUF;       // path A only: Wq,Wk,Wv contiguous
    u16* Wkb   = Wqb + WBUF;
    u16* Wvb   = Wkb + WBUF;
    u16* Wob   = Wqb;                // reuses Wq slot after QKV GEMM
    float* out = (float*)d_out;

    const int M = 2 * S_LEN, N = EDIM, Kd = EDIM;
    const dim3 gqkv(N / 128, M / 128, 3);
    const dim3 gone(N / 128, M / 128, 1);
    const dim3 gattn(S_LEN / 128, 2 * NHEAD, 1);
    const bool fast = ws_size >= (size_t)(2 * BUF + 3 * WBUF) * sizeof(u16);

    if (fast) {
        conv_all<<<7168, 256, 0, stream>>>(x, Wq, Wk, Wv, xb, Wqb);
        gemm128<0, false><<<gqkv, 256, 0, stream>>>(
            xb, Wqb, Wkb, Wvb, Q, Kb, VT, nullptr, M, N, Kd);
        f32_to_bf16<<<(int)(WBUF / 1024), 256, 0, stream>>>(Wo, Wob, (int)WBUF);
        attn2<<<gattn, 256, 0, stream>>>(Q, Kb, VT, qp, mixed);
        gemm128<2, false><<<gone, 256, 0, stream>>>(
            mixed, Wob, Wob, Wob, nullptr, nullptr, nullptr, out, M, N, Kd);
    } else {
        f32_to_bf16<<<(int)(BUF / 1024), 256, 0, stream>>>(x, xb, (int)BUF);
        gemm128<0, true><<<gqkv, 256, 0, stream>>>(
            xb, Wq, Wk, Wv, Q, Kb, VT, nullptr, M, N, Kd);
        attn2<<<gattn, 256, 0, stream>>>(Q, Kb, VT, qp, mixed);
        gemm128<2, true><<<gone, 256, 0, stream>>>(
            mixed, Wo, Wo, Wo, nullptr, nullptr, nullptr, out, M, N, Kd);
    }
}